// Round 6
// baseline (3891.860 us; speedup 1.0000x reference)
//
// ROUND 6: round-5 anchor with ONE change — output written as FLOAT32.
// Theory: reference output dtype is f32 ("else float*" harness rule); rounds
// 0-5 wrote bf16 ushorts into an f32 buffer -> deterministic misread explains
// the bit-identical 0.1828 errors across four different implementations.
#include <hip/hip_runtime.h>
#include <cstdint>

#define DEV __device__ __forceinline__

constexpr float SCL   = 0.35355339059327379f;   // 64^-0.25, tau=1
constexpr float RATIO = 0.18257418583505536f;   // 1/sqrt(30)
constexpr float EPS1  = 1e-6f;

// B=16 T=4096 N=65536 C_IN=128 H=8 D=64 M=30
// workspace (bytes):
constexpr size_t OF_PHIQ = 0;          // [65536][8][32] f32 = 67108864
constexpr size_t OF_KVS  = 67108864;   // [128][32][64] f32 = 1048576
constexpr size_t OF_KSUM = 68157440;   // [128][32] f32 = 16384
constexpr size_t OF_MK   = 68173824;   // 128 u32
constexpr size_t OF_MX   = 68174336;   // 128 f32
constexpr size_t WS_NEED = 68174848;

// ---- P1: Q-transform (phi_q, per-token max) + K global-max scan ----
__global__ __launch_bounds__(256) void p1(
    const float* __restrict__ x, const float* __restrict__ wq,
    const float* __restrict__ bq, const float* __restrict__ wk,
    const float* __restrict__ bk, const float* __restrict__ proj,
    float* __restrict__ phiq, unsigned* __restrict__ mk) {
  __shared__ float xs[64][129];
  __shared__ float dat[64][65];
  __shared__ float mx4[64][4];
  __shared__ float kred[256];
  int tid = threadIdx.x;
  int n0 = blockIdx.x * 64, b = n0 >> 12;
  {
    int row = tid >> 2, sg = tid & 3;
    for (int i = 0; i < 32; ++i)
      xs[row][sg * 32 + i] = x[(size_t)(n0 + row) * 128 + sg * 32 + i];
  }
  __syncthreads();
  int tok = tid & 63, grp = tid >> 6;   // grp in [0,4)

  for (int qk = 0; qk < 2; ++qk) {
    const float* W  = (qk == 0) ? wq : wk;
    const float* Bv = (qk == 0) ? bq : bk;
    for (int h = 0; h < 8; ++h) {
      for (int j = 0; j < 16; ++j) {
        int col = grp * 16 + j;
        const float* wrow = W + (size_t)(h * 64 + col) * 128;
        float a = Bv[h * 64 + col];
        for (int kk = 0; kk < 128; ++kk) a += xs[tok][kk] * wrow[kk];
        dat[tok][col] = a * SCL;
      }
      __syncthreads();
      float dg = 0.f;
      for (int d2 = 0; d2 < 64; ++d2) { float v = dat[tok][d2]; dg += v * v; }
      dg *= 0.5f;
      float ddv[8];
      float pm = -1e30f;
      for (int j = 0; j < 8; ++j) {
        int m = grp * 8 + j;
        float dd = 0.f;
        if (m < 30) {
          const float* pr = proj + (size_t)m * 64;
          for (int d2 = 0; d2 < 64; ++d2) dd += dat[tok][d2] * pr[d2];
          pm = fmaxf(pm, dd);
        }
        ddv[j] = dd;
      }
      if (qk == 0) {
        mx4[tok][grp] = pm;
        __syncthreads();
        float mxr = fmaxf(fmaxf(mx4[tok][0], mx4[tok][1]),
                          fmaxf(mx4[tok][2], mx4[tok][3]));
        for (int j = 0; j < 8; ++j) {
          int m = grp * 8 + j;
          float ph = (m < 30) ? (RATIO * (__expf(ddv[j] - dg - mxr) + EPS1)) : 0.f;
          phiq[((size_t)(n0 + tok) * 8 + h) * 32 + m] = ph;
        }
        __syncthreads();
      } else {
        kred[tid] = pm;
        __syncthreads();
        for (int s = 128; s > 0; s >>= 1) {
          if (tid < s) kred[tid] = fmaxf(kred[tid], kred[tid + s]);
          __syncthreads();
        }
        if (tid == 0) {
          unsigned u = __builtin_bit_cast(unsigned, kred[0]);
          unsigned key = (u & 0x80000000u) ? ~u : (u | 0x80000000u);
          atomicMax(&mk[b * 8 + h], key);
        }
        __syncthreads();
      }
    }
  }
}

// ---- P2: decode per-(b,h) max ----
__global__ void p2(const unsigned* __restrict__ mk, float* __restrict__ mx) {
  int i = threadIdx.x;
  if (i < 128) {
    unsigned k = mk[i];
    unsigned u = (k & 0x80000000u) ? (k & 0x7fffffffu) : ~k;
    mx[i] = __builtin_bit_cast(float, u);
  }
}

// ---- P3: recompute K,V; accumulate kvs[bh][m][d], ksum[bh][m] ----
__global__ __launch_bounds__(256) void p3(
    const float* __restrict__ x, const float* __restrict__ wk,
    const float* __restrict__ bk, const float* __restrict__ wv,
    const float* __restrict__ bv, const float* __restrict__ proj,
    const float* __restrict__ mx, float* __restrict__ kvs,
    float* __restrict__ ksum) {
  __shared__ float xs[64][129];
  __shared__ float dat[64][65];   // holds K data, then reused for V
  __shared__ float phk[64][33];
  int tid = threadIdx.x;
  int n0 = blockIdx.x * 64, b = n0 >> 12;
  {
    int row = tid >> 2, sg = tid & 3;
    for (int i = 0; i < 32; ++i)
      xs[row][sg * 32 + i] = x[(size_t)(n0 + row) * 128 + sg * 32 + i];
  }
  __syncthreads();
  int tok = tid & 63, grp = tid >> 6;

  for (int h = 0; h < 8; ++h) {
    float mxv = mx[b * 8 + h];
    for (int j = 0; j < 16; ++j) {
      int col = grp * 16 + j;
      const float* wrow = wk + (size_t)(h * 64 + col) * 128;
      float a = bk[h * 64 + col];
      for (int kk = 0; kk < 128; ++kk) a += xs[tok][kk] * wrow[kk];
      dat[tok][col] = a * SCL;
    }
    __syncthreads();
    float dg = 0.f;
    for (int d2 = 0; d2 < 64; ++d2) { float v = dat[tok][d2]; dg += v * v; }
    dg *= 0.5f;
    for (int j = 0; j < 8; ++j) {
      int m = grp * 8 + j;
      float ph = 0.f;
      if (m < 30) {
        float dd = 0.f;
        const float* pr = proj + (size_t)m * 64;
        for (int d2 = 0; d2 < 64; ++d2) dd += dat[tok][d2] * pr[d2];
        ph = RATIO * (__expf(dd - dg - mxv) + EPS1);
      }
      phk[tok][m] = ph;
    }
    __syncthreads();
    for (int j = 0; j < 16; ++j) {
      int col = grp * 16 + j;
      const float* wrow = wv + (size_t)(h * 64 + col) * 128;
      float a = bv[h * 64 + col];
      for (int kk = 0; kk < 128; ++kk) a += xs[tok][kk] * wrow[kk];
      dat[tok][col] = a;   // unscaled
    }
    __syncthreads();
    {
      int m = tid & 31, dgi = tid >> 5;
      float a8[8] = {0, 0, 0, 0, 0, 0, 0, 0};
      for (int t = 0; t < 64; ++t) {
        float p = phk[t][m];
        for (int j = 0; j < 8; ++j) a8[j] += p * dat[t][dgi * 8 + j];
      }
      size_t base = ((size_t)(b * 8 + h) * 32 + m) * 64 + dgi * 8;
      for (int j = 0; j < 8; ++j) atomicAdd(&kvs[base + j], a8[j]);
    }
    if (tid < 32) {
      float s = 0.f;
      for (int t = 0; t < 64; ++t) s += phk[t][tid];
      atomicAdd(&ksum[(b * 8 + h) * 32 + tid], s);
    }
    __syncthreads();
  }
}

// ---- P4: attn = (phi_q @ kvs)/den per head, then @ wo^T + bias ----
__global__ __launch_bounds__(256) void p4(
    const float* __restrict__ phiq, const float* __restrict__ kvs,
    const float* __restrict__ ksum, const float* __restrict__ wo,
    const float* __restrict__ wob, float* __restrict__ out) {
  __shared__ float kv[32][65];
  __shared__ float ks[32];
  __shared__ float attn[64][65];
  int tid = threadIdx.x;
  int n0 = blockIdx.x * 64, b = n0 >> 12;
  int tok = tid & 63, grp = tid >> 6;
  float oacc[16];
  for (int j = 0; j < 16; ++j) oacc[j] = 0.f;

  for (int h = 0; h < 8; ++h) {
    int bh = b * 8 + h;
    __syncthreads();
    for (int i = tid; i < 2048; i += 256) kv[i >> 6][i & 63] = kvs[(size_t)bh * 2048 + i];
    if (tid < 32) ks[tid] = ksum[bh * 32 + tid];
    __syncthreads();
    float ph[30];
    const float* psrc = phiq + ((size_t)(n0 + tok) * 8 + h) * 32;
    float den = 0.f;
    for (int m = 0; m < 30; ++m) { ph[m] = psrc[m]; den += ph[m] * ks[m]; }
    float rd = 1.0f / den;
    for (int j = 0; j < 16; ++j) {
      int d = grp * 16 + j;
      float nm = 0.f;
      for (int m = 0; m < 30; ++m) nm += ph[m] * kv[m][d];
      attn[tok][d] = nm * rd;
    }
    __syncthreads();
    for (int j = 0; j < 16; ++j) {
      int c = grp * 16 + j;
      const float* wrow = wo + (size_t)c * 512 + h * 64;
      float s = 0.f;
      for (int d = 0; d < 64; ++d) s += attn[tok][d] * wrow[d];
      oacc[j] += s;
    }
  }
  for (int j = 0; j < 16; ++j) {
    int c = grp * 16 + j;
    out[(size_t)(n0 + tok) * 64 + c] = oacc[j] + wob[c];   // FLOAT32 output
  }
}

extern "C" void kernel_launch(void* const* d_in, const int* in_sizes, int n_in,
                              void* d_out, int out_size, void* d_ws, size_t ws_size,
                              hipStream_t stream) {
  const int expect[10] = {8388608, 65536, 512, 65536, 512, 65536, 512, 32768, 64, 1920};
  if (n_in != 10) return;
  for (int i = 0; i < 10; ++i) if (in_sizes[i] != expect[i]) return;
  if (out_size != 4194304) return;
  if (ws_size < WS_NEED) return;

  const float* x    = (const float*)d_in[0];
  const float* wq   = (const float*)d_in[1];
  const float* bq   = (const float*)d_in[2];
  const float* wk   = (const float*)d_in[3];
  const float* bk   = (const float*)d_in[4];
  const float* wv   = (const float*)d_in[5];
  const float* bv   = (const float*)d_in[6];
  const float* wo   = (const float*)d_in[7];
  const float* wob  = (const float*)d_in[8];
  const float* proj = (const float*)d_in[9];

  char* ws = (char*)d_ws;
  float*    phiq = (float*)(ws + OF_PHIQ);
  float*    kvs  = (float*)(ws + OF_KVS);
  float*    ksum = (float*)(ws + OF_KSUM);
  unsigned* mk   = (unsigned*)(ws + OF_MK);
  float*    mx   = (float*)(ws + OF_MX);

  (void)hipMemsetAsync(ws + OF_KVS, 0, 1048576 + 16384 + 512, stream);

  p1<<<1024, 256, 0, stream>>>(x, wq, bq, wk, bk, proj, phiq, mk);
  p2<<<1, 128, 0, stream>>>(mk, mx);
  p3<<<1024, 256, 0, stream>>>(x, wk, bk, wv, bv, proj, mx, kvs, ksum);
  p4<<<1024, 256, 0, stream>>>(phiq, kvs, ksum, wo, wob, (float*)d_out);
}

// Round 7
// 222.829 us; speedup vs baseline: 17.4657x; 17.4657x over previous
//
// ROUND 7: fast MFMA pipeline (round-3 design) + the round-6 dtype fix
// (output is FLOAT32). R2(MFMA)≡R4/R5(VALU) bit-identical misread fingerprints
// established the MFMA chain computes the same function as the verified anchor.
#include <hip/hip_runtime.h>
#include <cstdint>

typedef __attribute__((ext_vector_type(4))) float f32x4;
typedef __attribute__((ext_vector_type(8))) short short8;
typedef __attribute__((ext_vector_type(4))) unsigned short us4;
typedef __attribute__((ext_vector_type(8))) unsigned short us8;

#define DEV __device__ __forceinline__

DEV unsigned short f2b(float f) {
  unsigned u = __builtin_bit_cast(unsigned, f);
  return (unsigned short)((u + 0x7fffu + ((u >> 16) & 1u)) >> 16);
}
DEV float b2f(unsigned short h) {
  unsigned u = ((unsigned)h) << 16;
  return __builtin_bit_cast(float, u);
}
DEV unsigned short f2h(float f) {
  _Float16 h = (_Float16)f;
  return __builtin_bit_cast(unsigned short, h);
}
DEV float h2f(unsigned short u) {
  return (float)__builtin_bit_cast(_Float16, u);
}

constexpr float SQ_SCALE = 0.35355339059327379f;    // 64^-0.25 (tau=1)
constexpr float RATIO    = 0.18257418583505536f;    // 1/sqrt(30)
constexpr float REPS     = 0.18257418583505536e-6f; // RATIO * 1e-6

// B=16, T=4096, N=65536, C_IN=128, H=8, D=64, M=30 (pad 32)
// Big GEMM B-matrix columns: [0,512) q | [512,1024) k | [1024,1536) v |
//   [1536,1792) ddq (h*32+m) | [1792,2048) ddk
constexpr size_t OF_WQKV   = 0;            // 2048*128 bf16
constexpr size_t OF_WBP    = 524288;       // 2048 f32
constexpr size_t OF_PHIQ   = 532480;       // 65536*8*32 bf16
constexpr size_t OF_SK     = 34086912;     // 65536*8*32 fp16 (reused as Gt after K3)
constexpr size_t OF_VT     = 67641344;     // 128*64*4096 bf16 [bh][d][t]
constexpr size_t OF_MAXKEY = 134750208;    // 128 u32
constexpr size_t OF_KVS    = 134750720;    // 128*32*64 f32
constexpr size_t OF_KSUM   = 135799296;    // 128*32 f32
constexpr size_t OF_MX     = 135815680;    // 128 f32
constexpr size_t OF_GT     = OF_SK;        // 128*64*32 bf16 [bh][c][m] (overlap)
constexpr size_t WS_NEED   = 135816192;

// ---------------- K0: pack weights + fold proj into Wq/Wk ----------------
__global__ __launch_bounds__(256) void k_pack(
    const float* __restrict__ wq, const float* __restrict__ wk,
    const float* __restrict__ wv, const float* __restrict__ bq,
    const float* __restrict__ bk, const float* __restrict__ bv,
    const float* __restrict__ proj,
    unsigned short* __restrict__ wqkv, float* __restrict__ wbp) {
  int bid = blockIdx.x, tid = threadIdx.x;
  if (bid < 768) {
    int id = bid * 256 + tid;          // 0..196607 -> cols 0..1535
    int c = id >> 7, k = id & 127;
    int mat = c >> 9, row = c & 511;
    const float* w = (mat == 0) ? wq : ((mat == 1) ? wk : wv);
    float s = (mat < 2) ? SQ_SCALE : 1.0f;
    wqkv[id] = f2b(w[row * 128 + k] * s);
  } else if (bid < 784) {
    // fold: P_h[m][k] = sum_d proj[m][d] * W_scaled[h*64+d][k]
    __shared__ float wsm[64 * 128];
    __shared__ float ps[32 * 64];
    __shared__ float bs[64];
    int db = bid - 768, mat2 = db >> 3, h = db & 7;
    const float* wsrc = (mat2 == 0) ? wq : wk;
    const float* bsrc = (mat2 == 0) ? bq : bk;
    for (int i = tid; i < 8192; i += 256) wsm[i] = wsrc[h * 8192 + i] * SQ_SCALE;
    for (int i = tid; i < 2048; i += 256) {
      int m = i >> 6, d = i & 63;
      ps[i] = (m < 30) ? proj[m * 64 + d] : 0.0f;
    }
    if (tid < 64) bs[tid] = bsrc[h * 64 + tid] * SQ_SCALE;
    __syncthreads();
    int m = tid >> 3, kseg = tid & 7;
    int col = 1536 + mat2 * 256 + h * 32 + m;
#pragma unroll 4
    for (int kk = 0; kk < 16; ++kk) {
      int k = kseg * 16 + kk;
      float a = 0.f;
      for (int d = 0; d < 64; ++d) a += ps[m * 64 + d] * wsm[d * 128 + k];
      wqkv[col * 128 + k] = f2b(a);
    }
    if (tid < 32) {
      float a = 0.f;
      for (int d = 0; d < 64; ++d) a += ps[tid * 64 + d] * bs[d];
      wbp[1536 + mat2 * 256 + h * 32 + tid] = a;
    }
  } else {
    for (int i = tid; i < 1536; i += 256) {
      int mat = i >> 9, row = i & 511;
      const float* bb = (mat == 0) ? bq : ((mat == 1) ? bk : bv);
      wbp[i] = bb[row] * ((mat < 2) ? SQ_SCALE : 1.0f);
    }
  }
}

// ---------------- K1: one fused GEMM -> diag, v, phi_q, s_k, k-max ----------------
__global__ __launch_bounds__(256) void k_qkv(
    const float* __restrict__ x, const unsigned short* __restrict__ wqkv,
    const float* __restrict__ wbp,
    unsigned short* __restrict__ phiq, unsigned short* __restrict__ sk,
    unsigned short* __restrict__ vt, unsigned* __restrict__ maxkey) {
  __shared__ unsigned short xs[64 * 128];  // 16KB swizzled bf16 x-tile
  __shared__ float diag_s[2][512];         // [q|k][h*64 + tok]

  int tid = threadIdx.x;
  int w = tid >> 6, l = tid & 63;
  int g = l >> 4, li = l & 15;
  int n0 = blockIdx.x * 64;
  int b = n0 >> 12;
  int tloc = n0 & 4095;

  // stage x tile -> bf16 LDS (swizzled)
  {
    int row = tid >> 2, seg = tid & 3;
    const float* src = x + (size_t)(n0 + row) * 128 + seg * 32;
#pragma unroll
    for (int q8 = 0; q8 < 4; ++q8) {
      f32x4 a = *reinterpret_cast<const f32x4*>(src + q8 * 8);
      f32x4 c = *reinterpret_cast<const f32x4*>(src + q8 * 8 + 4);
      us8 o;
      o[0] = f2b(a[0]); o[1] = f2b(a[1]); o[2] = f2b(a[2]); o[3] = f2b(a[3]);
      o[4] = f2b(c[0]); o[5] = f2b(c[1]); o[6] = f2b(c[2]); o[7] = f2b(c[3]);
      int byte = (row * 256 + seg * 64 + q8 * 16) ^ ((row & 7) << 4);
      *reinterpret_cast<us8*>(((char*)xs) + byte) = o;
    }
  }
  __syncthreads();

  const short* wq_s = reinterpret_cast<const short*>(wqkv);

  for (int j = 0; j < 8; ++j) {
    if (j == 6) __syncthreads();   // diag_s complete before dd tiles
    int tl = j * 4 + w;            // wave w: q{w,4+w} k{8+w,12+w} v{16+w,20+w} ddq{24+w} ddk{28+w}
    int bcol = tl * 64;

    f32x4 acc[4][4] = {};
#pragma unroll
    for (int ks = 0; ks < 4; ++ks) {
      short8 a[4], bb[4];
#pragma unroll
      for (int fi = 0; fi < 4; ++fi) {
        int tokl = fi * 16 + li;
        int byte = (tokl * 256 + (ks * 32 + g * 8) * 2) ^ ((tokl & 7) << 4);
        a[fi] = *reinterpret_cast<const short8*>(((const char*)xs) + byte);
      }
#pragma unroll
      for (int fj = 0; fj < 4; ++fj)
        bb[fj] = *reinterpret_cast<const short8*>(wq_s + (bcol + fj * 16 + li) * 128 + ks * 32 + g * 8);
#pragma unroll
      for (int fi = 0; fi < 4; ++fi)
#pragma unroll
        for (int fj = 0; fj < 4; ++fj)
          acc[fi][fj] = __builtin_amdgcn_mfma_f32_16x16x32_bf16(a[fi], bb[fj], acc[fi][fj], 0, 0, 0);
    }
#pragma unroll
    for (int fj = 0; fj < 4; ++fj) {
      float bias = wbp[bcol + fj * 16 + li];
#pragma unroll
      for (int fi = 0; fi < 4; ++fi)
#pragma unroll
        for (int r = 0; r < 4; ++r) acc[fi][fj][r] += bias;
    }

    if (j < 4) {
      // q or k tile: only need diag = 0.5*sum_d data^2 per token
      int qk = j >> 1;
      int h = tl - qk * 8;
      float t4[4][4];
#pragma unroll
      for (int fi = 0; fi < 4; ++fi)
#pragma unroll
        for (int r = 0; r < 4; ++r) {
          float s = 0.f;
#pragma unroll
          for (int fj = 0; fj < 4; ++fj) { float v = acc[fi][fj][r]; s += v * v; }
          t4[fi][r] = s;
        }
#pragma unroll
      for (int mask = 1; mask <= 8; mask <<= 1)
#pragma unroll
        for (int fi = 0; fi < 4; ++fi)
#pragma unroll
          for (int r = 0; r < 4; ++r)
            t4[fi][r] += __shfl_xor(t4[fi][r], mask, 64);
      if (li == 0) {
#pragma unroll
        for (int fi = 0; fi < 4; ++fi)
#pragma unroll
          for (int r = 0; r < 4; ++r)
            diag_s[qk][h * 64 + fi * 16 + g * 4 + r] = 0.5f * t4[fi][r];
      }
    } else if (j < 6) {
      // v: store transposed [bh][d][t]
      int h = tl - 16;
      size_t base = (size_t)(b * 8 + h) * 64;
#pragma unroll
      for (int fi = 0; fi < 4; ++fi)
#pragma unroll
        for (int fj = 0; fj < 4; ++fj) {
          int d = fj * 16 + li;
          us4 o;
          o[0] = f2b(acc[fi][fj][0]); o[1] = f2b(acc[fi][fj][1]);
          o[2] = f2b(acc[fi][fj][2]); o[3] = f2b(acc[fi][fj][3]);
          *reinterpret_cast<us4*>(vt + (base + d) * 4096 + tloc + fi * 16 + g * 4) = o;
        }
    } else if (j == 6) {
      // ddq: cols = 2 heads x 32 m ; phi_q = ratio*(exp(dd - diag - rowmax) + eps)
      bool mv1 = (li < 14);
#pragma unroll
      for (int hp = 0; hp < 2; ++hp) {
        int h = (tl - 24) * 2 + hp;
        float mx4[4][4];
#pragma unroll
        for (int fi = 0; fi < 4; ++fi)
#pragma unroll
          for (int r = 0; r < 4; ++r)
            mx4[fi][r] = fmaxf(acc[fi][hp * 2][r], mv1 ? acc[fi][hp * 2 + 1][r] : -1e30f);
#pragma unroll
        for (int mask = 1; mask <= 8; mask <<= 1)
#pragma unroll
          for (int fi = 0; fi < 4; ++fi)
#pragma unroll
            for (int r = 0; r < 4; ++r)
              mx4[fi][r] = fmaxf(mx4[fi][r], __shfl_xor(mx4[fi][r], mask, 64));
#pragma unroll
        for (int fj2 = 0; fj2 < 2; ++fj2) {
          int m = fj2 * 16 + li;
          bool valid = (m < 30);
#pragma unroll
          for (int fi = 0; fi < 4; ++fi)
#pragma unroll
            for (int r = 0; r < 4; ++r) {
              int tok = fi * 16 + g * 4 + r;
              float ph = valid
                  ? (RATIO * __expf(acc[fi][hp * 2 + fj2][r] - diag_s[0][h * 64 + tok] - mx4[fi][r]) + REPS)
                  : 0.0f;
              phiq[((size_t)(n0 + tok) * 8 + h) * 32 + m] = f2b(ph);
            }
        }
      }
    } else {
      // ddk: record global per-(b,h) max of dd, store s_k = dd - diag (fp16)
      bool mv1 = (li < 14);
#pragma unroll
      for (int hp = 0; hp < 2; ++hp) {
        int h = (tl - 28) * 2 + hp;
        float km = -1e30f;
#pragma unroll
        for (int fi = 0; fi < 4; ++fi)
#pragma unroll
          for (int r = 0; r < 4; ++r) {
            km = fmaxf(km, acc[fi][hp * 2][r]);
            if (mv1) km = fmaxf(km, acc[fi][hp * 2 + 1][r]);
          }
#pragma unroll
        for (int mask = 1; mask <= 32; mask <<= 1)
          km = fmaxf(km, __shfl_xor(km, mask, 64));
        if (l == 0) {
          unsigned u = __builtin_bit_cast(unsigned, km);
          unsigned key = (u & 0x80000000u) ? ~u : (u | 0x80000000u);
          atomicMax(&maxkey[b * 8 + h], key);
        }
#pragma unroll
        for (int fj2 = 0; fj2 < 2; ++fj2) {
          int m = fj2 * 16 + li;
          bool valid = (m < 30);
#pragma unroll
          for (int fi = 0; fi < 4; ++fi)
#pragma unroll
            for (int r = 0; r < 4; ++r) {
              int tok = fi * 16 + g * 4 + r;
              float sv = valid ? (acc[fi][hp * 2 + fj2][r] - diag_s[1][h * 64 + tok]) : 0.0f;
              sk[((size_t)(n0 + tok) * 8 + h) * 32 + m] = f2h(sv);
            }
        }
      }
    }
  }
}

// ---------------- K2: finalize per-(b,h) max ----------------
__global__ void k_finmax(const unsigned* __restrict__ maxkey, float* __restrict__ mx) {
  int i = threadIdx.x;
  if (i < 128) {
    unsigned k = maxkey[i];
    unsigned u = (k & 0x80000000u) ? (k & 0x7fffffffu) : ~k;
    mx[i] = __builtin_bit_cast(float, u);
  }
}

// ---------------- K3: kvs += phi_k^T @ v, ksum += sum phi_k ----------------
__global__ __launch_bounds__(256) void k_kvs(
    const unsigned short* __restrict__ sk, const unsigned short* __restrict__ vt,
    const float* __restrict__ mx, float* __restrict__ kvs, float* __restrict__ ksum) {
  __shared__ unsigned short phit[32 * 64];  // [m][tok] bf16, swizzled
  __shared__ unsigned short vts[64 * 64];   // [d][tok] bf16, swizzled
  __shared__ float ksums[32];

  int tid = threadIdx.x;
  int w = tid >> 6, l = tid & 63, g = l >> 4, li = l & 15;
  int bid = blockIdx.x;
  int bh = bid >> 2, chunk = bid & 3;
  int b = bh >> 3, h = bh & 7;
  float mxv = mx[bh];
  if (tid < 32) ksums[tid] = 0.f;

  int ptok = tid & 63;
  int mseg = tid >> 6;
  float kpart[8] = {0, 0, 0, 0, 0, 0, 0, 0};
  f32x4 acc[2] = {};
  int tok0 = chunk * 1024;

  for (int tile = 0; tile < 16; ++tile) {
    int t0 = tok0 + tile * 64;
    __syncthreads();
    {
      int n = b * 4096 + t0 + ptok;
      us8 s8 = *reinterpret_cast<const us8*>(sk + ((size_t)n * 8 + h) * 32 + mseg * 8);
#pragma unroll
      for (int j = 0; j < 8; ++j) {
        int m = mseg * 8 + j;
        float ph = 0.f;
        if (m < 30) ph = RATIO * __expf(h2f(s8[j]) - mxv) + REPS;
        kpart[j] += ph;
        int byte = (m * 128 + ptok * 2) ^ ((m & 7) << 4);
        *reinterpret_cast<unsigned short*>(((char*)phit) + byte) = f2b(ph);
      }
    }
    {
      int d = tid >> 2, seg = tid & 3;
      const unsigned short* src = vt + ((size_t)bh * 64 + d) * 4096 + t0 + seg * 16;
      us8 v0 = *reinterpret_cast<const us8*>(src);
      us8 v1 = *reinterpret_cast<const us8*>(src + 8);
      int byte0 = (d * 128 + seg * 32) ^ ((d & 7) << 4);
      int byte1 = (d * 128 + seg * 32 + 16) ^ ((d & 7) << 4);
      *reinterpret_cast<us8*>(((char*)vts) + byte0) = v0;
      *reinterpret_cast<us8*>(((char*)vts) + byte1) = v1;
    }
    __syncthreads();
#pragma unroll
    for (int ks = 0; ks < 2; ++ks) {
      int byteA0 = (li * 128 + (ks * 32 + g * 8) * 2) ^ ((li & 7) << 4);
      int byteA1 = ((16 + li) * 128 + (ks * 32 + g * 8) * 2) ^ ((li & 7) << 4);
      int dcol = w * 16 + li;
      int byteB = (dcol * 128 + (ks * 32 + g * 8) * 2) ^ ((dcol & 7) << 4);
      short8 a0 = *reinterpret_cast<const short8*>(((const char*)phit) + byteA0);
      short8 a1 = *reinterpret_cast<const short8*>(((const char*)phit) + byteA1);
      short8 bb = *reinterpret_cast<const short8*>(((const char*)vts) + byteB);
      acc[0] = __builtin_amdgcn_mfma_f32_16x16x32_bf16(a0, bb, acc[0], 0, 0, 0);
      acc[1] = __builtin_amdgcn_mfma_f32_16x16x32_bf16(a1, bb, acc[1], 0, 0, 0);
    }
  }
#pragma unroll
  for (int fm = 0; fm < 2; ++fm)
#pragma unroll
    for (int r = 0; r < 4; ++r) {
      int m = fm * 16 + g * 4 + r;
      int d = w * 16 + li;
      atomicAdd(&kvs[(size_t)bh * 2048 + m * 64 + d], acc[fm][r]);
    }
#pragma unroll
  for (int j = 0; j < 8; ++j) atomicAdd(&ksums[mseg * 8 + j], kpart[j]);
  __syncthreads();
  if (tid < 32) atomicAdd(&ksum[bh * 32 + tid], ksums[tid]);
}

// ---------------- K3b: fold Wo into kvs: Gt[bh][c][m] ----------------
__global__ __launch_bounds__(256) void k_fold(
    const float* __restrict__ kvs, const float* __restrict__ wo,
    unsigned short* __restrict__ Gt) {
  __shared__ float kv[32 * 64];
  __shared__ float wos[64 * 64];  // [d][c]
  int tid = threadIdx.x;
  int bh = blockIdx.x, h = bh & 7;
  for (int i = tid; i < 2048; i += 256) kv[i] = kvs[(size_t)bh * 2048 + i];
  {
    int c = tid >> 2, dseg = tid & 3;
#pragma unroll
    for (int jj = 0; jj < 16; ++jj) {
      int d = dseg * 16 + jj;
      wos[d * 64 + c] = wo[c * 512 + h * 64 + d];
    }
  }
  __syncthreads();
  int c = tid & 63, mseg = tid >> 6;
  us8 outv;
#pragma unroll
  for (int jj = 0; jj < 8; ++jj) {
    int m = mseg * 8 + jj;
    float a = 0.f;
    for (int d = 0; d < 64; ++d) a += kv[m * 64 + d] * wos[d * 64 + c];
    outv[jj] = f2b(a);
  }
  *reinterpret_cast<us8*>(Gt + ((size_t)bh * 64 + c) * 32 + mseg * 8) = outv;
}

// ---------------- K4: out = sum_h (phi_q @ G_h^T)/den_h + bias (f32 out) ----------------
__global__ __launch_bounds__(256) void k_out(
    const unsigned short* __restrict__ phiq, const unsigned short* __restrict__ Gt,
    const float* __restrict__ ksum, const float* __restrict__ wob,
    float* __restrict__ out) {
  int tid = threadIdx.x;
  int w = tid >> 6, l = tid & 63, g = l >> 4, li = l & 15;
  int n0 = blockIdx.x * 64 + w * 16;
  int b = (blockIdx.x * 64) >> 12;
  const short* phi_s = reinterpret_cast<const short*>(phiq);
  const short* gt_s = reinterpret_cast<const short*>(Gt);
  f32x4 oacc[4] = {};
#pragma unroll
  for (int h = 0; h < 8; ++h) {
    int bh = b * 8 + h;
    int tok = n0 + li;
    short8 a = *reinterpret_cast<const short8*>(phi_s + ((size_t)tok * 8 + h) * 32 + g * 8);
    const float* ksrow = ksum + bh * 32 + g * 8;
    float den = 0.f;
#pragma unroll
    for (int jj = 0; jj < 8; ++jj) den += b2f((unsigned short)a[jj]) * ksrow[jj];
    den += __shfl_xor(den, 16, 64);
    den += __shfl_xor(den, 32, 64);
    float rd = 1.0f / den;
    f32x4 nm[4];
#pragma unroll
    for (int fj = 0; fj < 4; ++fj) {
      short8 bb = *reinterpret_cast<const short8*>(gt_s + ((size_t)bh * 64 + fj * 16 + li) * 32 + g * 8);
      f32x4 z = {};
      nm[fj] = __builtin_amdgcn_mfma_f32_16x16x32_bf16(a, bb, z, 0, 0, 0);
    }
#pragma unroll
    for (int r = 0; r < 4; ++r) {
      float rdr = __shfl(rd, g * 4 + r, 64);
#pragma unroll
      for (int fj = 0; fj < 4; ++fj) oacc[fj][r] += nm[fj][r] * rdr;
    }
  }
#pragma unroll
  for (int fj = 0; fj < 4; ++fj) {
    float bias = wob[fj * 16 + li];
#pragma unroll
    for (int r = 0; r < 4; ++r) {
      int n = n0 + g * 4 + r;
      out[(size_t)n * 64 + fj * 16 + li] = oacc[fj][r] + bias;   // FLOAT32 output
    }
  }
}

extern "C" void kernel_launch(void* const* d_in, const int* in_sizes, int n_in,
                              void* d_out, int out_size, void* d_ws, size_t ws_size,
                              hipStream_t stream) {
  const int expect[10] = {8388608, 65536, 512, 65536, 512, 65536, 512, 32768, 64, 1920};
  if (n_in != 10) return;
  for (int i = 0; i < 10; ++i) if (in_sizes[i] != expect[i]) return;
  if (out_size != 4194304) return;
  if (ws_size < WS_NEED) return;

  const float* x    = (const float*)d_in[0];
  const float* wq   = (const float*)d_in[1];
  const float* bq   = (const float*)d_in[2];
  const float* wk   = (const float*)d_in[3];
  const float* bk   = (const float*)d_in[4];
  const float* wv   = (const float*)d_in[5];
  const float* bv   = (const float*)d_in[6];
  const float* wo   = (const float*)d_in[7];
  const float* wob  = (const float*)d_in[8];
  const float* proj = (const float*)d_in[9];

  char* ws = (char*)d_ws;
  unsigned short* wqkv = (unsigned short*)(ws + OF_WQKV);
  float*          wbp  = (float*)(ws + OF_WBP);
  unsigned short* phiq = (unsigned short*)(ws + OF_PHIQ);
  unsigned short* sk   = (unsigned short*)(ws + OF_SK);
  unsigned short* vt   = (unsigned short*)(ws + OF_VT);
  unsigned*       mkey = (unsigned*)(ws + OF_MAXKEY);
  float*          kvs  = (float*)(ws + OF_KVS);
  float*          ksum = (float*)(ws + OF_KSUM);
  float*          mx   = (float*)(ws + OF_MX);
  unsigned short* Gt   = (unsigned short*)(ws + OF_GT);

  (void)hipMemsetAsync(ws + OF_MAXKEY, 0, 512 + 1048576 + 16384, stream);

  k_pack<<<785, 256, 0, stream>>>(wq, wk, wv, bq, bk, bv, proj, wqkv, wbp);
  k_qkv<<<1024, 256, 0, stream>>>(x, wqkv, wbp, phiq, sk, vt, mkey);
  k_finmax<<<1, 128, 0, stream>>>(mkey, mx);
  k_kvs<<<512, 256, 0, stream>>>(sk, vt, mx, kvs, ksum);
  k_fold<<<128, 256, 0, stream>>>(kvs, wo, Gt);
  k_out<<<1024, 256, 0, stream>>>(phiq, Gt, ksum, wob, (float*)d_out);
}